// Round 2
// baseline (558.458 us; speedup 1.0000x reference)
//
#include <hip/hip_runtime.h>
#include <hip/hip_bf16.h>
#include <cstdint>

#define N_NODES 50000
#define N_EDGES 800000
#define D_IN 128
#define D_HID 256
#define D_OUT 128

// Source-window partition for L2-resident gathers:
// window = src >> 13 (8192 rows = 2 MB of bf16 xb per window), 7 windows.
#define WIN_SHIFT 13
#define N_WIN ((N_NODES + (1 << WIN_SHIFT) - 1) >> WIN_SHIFT)  // 7

typedef __bf16 bf16;
typedef __bf16 bf16x8 __attribute__((ext_vector_type(8)));
typedef __bf16 bf16x4 __attribute__((ext_vector_type(4)));
typedef float f32x4 __attribute__((ext_vector_type(4)));

// ---------------------------------------------------------------------------
// Kernel 1: prep + CSR fused.
//  - xb = bf16(x)                (vectorized float4 -> bf16x4)
//  - w1t/w2t transposed bf16 weights
//  - offs[] CSR row offsets from SORTED edge_dst (boundary scatter)
// grid: 6250 x 256 covers N*D_IN/4 = 1.6M exactly; threads < 800k also do CSR.
// ---------------------------------------------------------------------------
__global__ __launch_bounds__(256) void prep_csr_kernel(
    const float* __restrict__ x, const int* __restrict__ dst,
    const float* __restrict__ w1, const float* __restrict__ w2,
    bf16* __restrict__ xb, bf16* __restrict__ w1t, bf16* __restrict__ w2t,
    int* __restrict__ offs) {
  const int i = blockIdx.x * 256 + threadIdx.x;
  float4 v = ((const float4*)x)[i];
  ((bf16x4*)xb)[i] = bf16x4{(bf16)v.x, (bf16)v.y, (bf16)v.z, (bf16)v.w};
  if (i < D_IN * D_HID) {            // 32768
    int k = i >> 8, n = i & 255;     // w1[k][n]
    w1t[n * D_IN + k] = (bf16)w1[i];
  } else if (i < 2 * D_IN * D_HID) { // next 32768
    int j = i - D_IN * D_HID;
    int k = j >> 7, n = j & 127;     // w2[k][n]
    w2t[n * D_HID + k] = (bf16)w2[j];
  }
  if (i < N_EDGES) {
    const int b = dst[i];
    const int a = (i == 0) ? -1 : dst[i - 1];
    for (int n = a + 1; n <= b; ++n) offs[n] = i;
    if (i == N_EDGES - 1)
      for (int n = b + 1; n <= N_NODES; ++n) offs[n] = N_EDGES;
  }
}

// ---------------------------------------------------------------------------
// Kernel 2: node-centric aggregation with SOURCE-WINDOWED sweeps.
// agg[n] = sum_e val_e * xb[src_e] + (1+eps)*xb[n], one wave per node, no
// atomics. The wave sweeps its edge run N_WIN times; sweep w gathers only
// edges whose src lies in window w (2 MB of xb). All waves sweep windows in
// the same order, so concurrent gathers on an XCD concentrate on ~1-2
// windows -> L2-resident (vs random over 12.8 MB -> LLC-random wall).
// Metadata loads are wave-uniform (scalarized, K$-hot on re-sweeps).
// Chunks of 16 with clamped masked loads: no serial remainder tail, masked
// slots gather nothing and contribute 0 (g=0, vv=0).
// fp32 accumulation across the whole node; one packed bf16x2 NT store/lane.
// ---------------------------------------------------------------------------
__global__ __launch_bounds__(256) void node_agg_kernel(
    const bf16* __restrict__ xb, const int* __restrict__ src,
    const float* __restrict__ val, const int* __restrict__ offs,
    const float* __restrict__ eps, bf16* __restrict__ aggb) {
  const int node = __builtin_amdgcn_readfirstlane(
      (blockIdx.x << 2) | (threadIdx.x >> 6));
  const int lane = threadIdx.x & 63;
  const int s = __builtin_amdgcn_readfirstlane(offs[node]);
  const int e = __builtin_amdgcn_readfirstlane(offs[node + 1]);

  float2 acc = make_float2(0.f, 0.f);

  if (e > s) {
    for (int w = 0; w < N_WIN; ++w) {
      for (int i = s; i < e; i += 16) {
        int sv[16]; float vv[16];
        #pragma unroll
        for (int t = 0; t < 16; ++t) {
          int idx = i + t; if (idx >= e) idx = e - 1;   // clamped (in-bounds)
          sv[t] = src[idx];
          vv[t] = val[idx];
        }
        int g[16];
        #pragma unroll
        for (int t = 0; t < 16; ++t) {
          // wave-uniform predicate: edge valid AND src in this window
          if ((i + t < e) && ((sv[t] >> WIN_SHIFT) == w)) {
            g[t] = *(const int*)&xb[(long)sv[t] * D_IN + lane * 2];
          } else {
            g[t] = 0; vv[t] = 0.f;
          }
        }
        #pragma unroll
        for (int t = 0; t < 16; ++t) {
          float gx = __uint_as_float((unsigned)g[t] << 16);
          float gy = __uint_as_float((unsigned)g[t] & 0xffff0000u);
          acc.x = fmaf(vv[t], gx, acc.x);
          acc.y = fmaf(vv[t], gy, acc.y);
        }
      }
    }
  }

  const float scale = 1.0f + eps[0];
  int xg = *(const int*)&xb[(long)node * D_IN + lane * 2];
  acc.x = fmaf(scale, __uint_as_float((unsigned)xg << 16), acc.x);
  acc.y = fmaf(scale, __uint_as_float((unsigned)xg & 0xffff0000u), acc.y);

  union { struct { bf16 x, y; } h; int i_; } u;
  u.h.x = (bf16)acc.x; u.h.y = (bf16)acc.y;
  __builtin_nontemporal_store(u.i_, (int*)&aggb[(long)node * D_IN + lane * 2]);
}

// ---------------------------------------------------------------------------
// Kernel 3: FUSED 2-layer MLP (unchanged structure; out stores nontemporal).
// out = relu(A@W1+b1)@W2 + b2, h lives only in LDS. 64 rows/block,
// W1/W2 fragments in registers straight from global (verified layouts:
//   A: a[j]=A[l15][quad*8+j]; B: b[j]=Wt[l15][quad*8+j]; C: row=quad*4+r,col=l15).
// LDS = 17.4KB (As) + 33.8KB (Hs) = 51.2KB -> 3 blocks/CU.
// ---------------------------------------------------------------------------
__global__ __launch_bounds__(256) void mlp_fused(
    const bf16* __restrict__ A, const bf16* __restrict__ W1t,
    const bf16* __restrict__ W2t, const float* __restrict__ b1,
    const float* __restrict__ b2, float* __restrict__ out) {
  constexpr int LDA = 136;  // 272B row stride: 2-way bank aliasing only
  constexpr int LDH = 264;  // 528B row stride: 2-way bank aliasing only
  __shared__ alignas(16) bf16 As[64][LDA];
  __shared__ alignas(16) bf16 Hs[64][LDH];

  const int tid = threadIdx.x;
  const int m0 = blockIdx.x * 64;
  const int wave = tid >> 6;
  const int lane = tid & 63;
  const int l15 = lane & 15;
  const int quad = lane >> 4;

  #pragma unroll
  for (int it = 0; it < 4; ++it) {
    int idx = tid + it * 256;          // 0..1023
    int r = idx >> 4;
    int c8 = (idx & 15) << 3;
    int row = m0 + r; if (row >= N_NODES) row = N_NODES - 1;
    *(bf16x8*)&As[r][c8] = *(const bf16x8*)&A[(long)row * D_IN + c8];
  }

  bf16x8 w1f[4][4];  // [nf][ks]
  #pragma unroll
  for (int nf = 0; nf < 4; ++nf) {
    int n = wave * 64 + nf * 16 + l15;
    #pragma unroll
    for (int ks = 0; ks < 4; ++ks)
      w1f[nf][ks] = *(const bf16x8*)&W1t[(long)n * D_IN + ks * 32 + quad * 8];
  }
  __syncthreads();

  // Phase 1: h[0:64, wave*64 : wave*64+64) = relu(A @ W1 + b1)
  f32x4 acc[4][4] = {};  // [mf][nf]
  #pragma unroll
  for (int ks = 0; ks < 4; ++ks) {
    int kq = ks * 32 + quad * 8;
    bf16x8 a[4];
    #pragma unroll
    for (int mf = 0; mf < 4; ++mf)
      a[mf] = *(const bf16x8*)&As[mf * 16 + l15][kq];
    #pragma unroll
    for (int mf = 0; mf < 4; ++mf)
      #pragma unroll
      for (int nf = 0; nf < 4; ++nf)
        acc[mf][nf] = __builtin_amdgcn_mfma_f32_16x16x32_bf16(
            a[mf], w1f[nf][ks], acc[mf][nf], 0, 0, 0);
  }

  #pragma unroll
  for (int nf = 0; nf < 4; ++nf) {
    int col = wave * 64 + nf * 16 + l15;
    float bv = b1[col];
    #pragma unroll
    for (int mf = 0; mf < 4; ++mf)
      #pragma unroll
      for (int r = 0; r < 4; ++r)
        Hs[mf * 16 + quad * 4 + r][col] = (bf16)fmaxf(acc[mf][nf][r] + bv, 0.f);
  }

  bf16x8 w2f[2][8];  // [nf2][ks2]
  #pragma unroll
  for (int nf2 = 0; nf2 < 2; ++nf2) {
    int n = wave * 32 + nf2 * 16 + l15;
    #pragma unroll
    for (int ks2 = 0; ks2 < 8; ++ks2)
      w2f[nf2][ks2] = *(const bf16x8*)&W2t[(long)n * D_HID + ks2 * 32 + quad * 8];
  }
  __syncthreads();

  // Phase 2: out[0:64, wave*32 : wave*32+32) = h @ W2 + b2
  f32x4 acc2[4][2] = {};  // [mf][nf2]
  #pragma unroll
  for (int ks2 = 0; ks2 < 8; ++ks2) {
    int kq = ks2 * 32 + quad * 8;
    bf16x8 ha[4];
    #pragma unroll
    for (int mf = 0; mf < 4; ++mf)
      ha[mf] = *(const bf16x8*)&Hs[mf * 16 + l15][kq];
    #pragma unroll
    for (int mf = 0; mf < 4; ++mf)
      #pragma unroll
      for (int nf2 = 0; nf2 < 2; ++nf2)
        acc2[mf][nf2] = __builtin_amdgcn_mfma_f32_16x16x32_bf16(
            ha[mf], w2f[nf2][ks2], acc2[mf][nf2], 0, 0, 0);
  }

  #pragma unroll
  for (int nf2 = 0; nf2 < 2; ++nf2) {
    int col = wave * 32 + nf2 * 16 + l15;
    float bv = b2[col];
    #pragma unroll
    for (int mf = 0; mf < 4; ++mf)
      #pragma unroll
      for (int r = 0; r < 4; ++r) {
        int row = m0 + mf * 16 + quad * 4 + r;
        if (row < N_NODES)
          __builtin_nontemporal_store(acc2[mf][nf2][r] + bv,
                                      &out[(long)row * D_OUT + col]);
      }
  }
}

// ---------------------------------------------------------------------------
extern "C" void kernel_launch(void* const* d_in, const int* in_sizes, int n_in,
                              void* d_out, int out_size, void* d_ws, size_t ws_size,
                              hipStream_t stream) {
  const float* x    = (const float*)d_in[0];
  const int*   esrc = (const int*)d_in[1];
  const int*   edst = (const int*)d_in[2];
  const float* evl  = (const float*)d_in[3];
  const float* eps  = (const float*)d_in[4];
  const float* w1   = (const float*)d_in[5];
  const float* b1   = (const float*)d_in[6];
  const float* w2   = (const float*)d_in[7];
  const float* b2   = (const float*)d_in[8];
  float* out = (float*)d_out;

  // workspace layout (16B aligned)
  bf16* aggb = (bf16*)d_ws;                          // 12.8 MB
  bf16* xb   = aggb + (size_t)N_NODES * D_IN;        // 12.8 MB
  bf16* w1t  = xb + (size_t)N_NODES * D_IN;          // 64 KB
  bf16* w2t  = w1t + D_IN * D_HID;                   // 64 KB
  int*  offs = (int*)(w2t + D_HID * D_OUT);          // 200 KB

  prep_csr_kernel<<<(N_NODES * D_IN / 4) / 256, 256, 0, stream>>>(
      x, edst, w1, w2, xb, w1t, w2t, offs);
  node_agg_kernel<<<(N_NODES + 3) / 4, 256, 0, stream>>>(
      xb, esrc, evl, offs, eps, aggb);
  mlp_fused<<<(N_NODES + 63) / 64, 256, 0, stream>>>(
      aggb, w1t, w2t, b1, b2, out);
}

// Round 3
// 203.155 us; speedup vs baseline: 2.7489x; 2.7489x over previous
//
#include <hip/hip_runtime.h>
#include <hip/hip_bf16.h>
#include <cstdint>

#define N_NODES 50000
#define N_EDGES 800000
#define D_IN 128
#define D_HID 256
#define D_OUT 128

typedef __bf16 bf16;
typedef __bf16 bf16x8 __attribute__((ext_vector_type(8)));
typedef __bf16 bf16x4 __attribute__((ext_vector_type(4)));
typedef float f32x4 __attribute__((ext_vector_type(4)));

__device__ __forceinline__ float bflo(int p) {
  return __uint_as_float((unsigned)p << 16);
}
__device__ __forceinline__ float bfhi(int p) {
  return __uint_as_float((unsigned)p & 0xffff0000u);
}
__device__ __forceinline__ int pack_bf2(float fx, float fy) {
  union { struct { bf16 x, y; } h; int i; } u;
  u.h.x = (bf16)fx; u.h.y = (bf16)fy;
  return u.i;
}

// ---------------------------------------------------------------------------
// Kernel 1: prep + CSR fused (unchanged from round 2 — passed, ~8 us).
//  - xb = bf16(x); w1t/w2t transposed bf16 weights;
//  - offs[] CSR row offsets from SORTED edge_dst (boundary scatter).
// grid: 6250 x 256 covers N*D_IN/4 = 1.6M exactly; threads < 800k also do CSR.
// ---------------------------------------------------------------------------
__global__ __launch_bounds__(256) void prep_csr_kernel(
    const float* __restrict__ x, const int* __restrict__ dst,
    const float* __restrict__ w1, const float* __restrict__ w2,
    bf16* __restrict__ xb, bf16* __restrict__ w1t, bf16* __restrict__ w2t,
    int* __restrict__ offs) {
  const int i = blockIdx.x * 256 + threadIdx.x;
  float4 v = ((const float4*)x)[i];
  ((bf16x4*)xb)[i] = bf16x4{(bf16)v.x, (bf16)v.y, (bf16)v.z, (bf16)v.w};
  if (i < D_IN * D_HID) {            // 32768
    int k = i >> 8, n = i & 255;     // w1[k][n]
    w1t[n * D_IN + k] = (bf16)w1[i];
  } else if (i < 2 * D_IN * D_HID) { // next 32768
    int j = i - D_IN * D_HID;
    int k = j >> 7, n = j & 127;     // w2[k][n]
    w2t[n * D_HID + k] = (bf16)w2[j];
  }
  if (i < N_EDGES) {
    const int b = dst[i];
    const int a = (i == 0) ? -1 : dst[i - 1];
    for (int n = a + 1; n <= b; ++n) offs[n] = i;
    if (i == N_EDGES - 1)
      for (int n = b + 1; n <= N_NODES; ++n) offs[n] = N_EDGES;
  }
}

// ---------------------------------------------------------------------------
// Kernel 2: FULLY FUSED GIN layer. Per block: 64 nodes.
// Phase A: each wave writes self-term (1+eps)*x bf16 into its 16 As rows
//          (covers zero-in-degree nodes).
// Phase B: edge streaming — wave w owns the contiguous CSR range of nodes
//          [base, base+16), base = m0+w*16. All dst in that range are the
//          wave's own As rows -> LDS flush, no atomics, no races.
//          16-deep chunks (16 gathers + 48 broadcast metadata loads in
//          flight), clamp+mask tail (masked: vv=0, dv=dst[e-1]==cur -> no
//          spurious flush). 4 rotating f32 accumulators break the FMA chain.
//          Self-term is prefetched at run START (xg) and folded at flush ->
//          single bf16 rounding per output, no flush-time load stall.
// Phase C: the round-1 MLP: h = relu(As@W1+b1) -> Hs (LDS only),
//          out = Hs@W2 + b2. W1/W2 fragments in registers from global.
// Fragment layouts (verified): A: a[j]=A[l15][quad*8+j];
//   B: b[j]=Wt[l15][quad*8+j]; C: row=quad*4+r, col=l15.
// LDS = 17.4KB (As) + 33.8KB (Hs) = 51.2KB -> 3 blocks/CU; 782 blocks.
// ---------------------------------------------------------------------------
__global__ __launch_bounds__(256) void gin_fused(
    const bf16* __restrict__ xb, const int* __restrict__ src,
    const int* __restrict__ dst, const float* __restrict__ val,
    const int* __restrict__ offs, const float* __restrict__ eps,
    const bf16* __restrict__ W1t, const bf16* __restrict__ W2t,
    const float* __restrict__ b1, const float* __restrict__ b2,
    float* __restrict__ out) {
  constexpr int LDA = 136;  // 272B row stride: 2-way bank aliasing only
  constexpr int LDH = 264;  // 528B row stride: 2-way bank aliasing only
  __shared__ alignas(16) bf16 As[64][LDA];
  __shared__ alignas(16) bf16 Hs[64][LDH];

  const int tid = threadIdx.x;
  const int m0 = blockIdx.x * 64;
  const int wave = tid >> 6;
  const int lane = tid & 63;
  const int l15 = lane & 15;
  const int quad = lane >> 4;
  const float scale = 1.0f + eps[0];
  const int base = m0 + wave * 16;

  // ---- Phase A: self-term into this wave's 16 As rows ----
  {
    int xgv[16];
    #pragma unroll
    for (int t = 0; t < 16; ++t) {
      int node = base + t; if (node >= N_NODES) node = N_NODES - 1;
      xgv[t] = *(const int*)&xb[(long)node * D_IN + lane * 2];
    }
    #pragma unroll
    for (int t = 0; t < 16; ++t)
      *(int*)&As[wave * 16 + t][lane * 2] =
          pack_bf2(scale * bflo(xgv[t]), scale * bfhi(xgv[t]));
  }

  // ---- Phase B: stream this wave's contiguous edge range ----
  if (base < N_NODES) {
    const int nend = (base + 16 < N_NODES) ? base + 16 : N_NODES;
    const int s = __builtin_amdgcn_readfirstlane(offs[base]);
    const int e = __builtin_amdgcn_readfirstlane(offs[nend]);
    if (e > s) {
      int cur = __builtin_amdgcn_readfirstlane(dst[s]);
      // prefetch self-row of current run's node; consumed at its flush
      int xg = *(const int*)&xb[(long)cur * D_IN + lane * 2];
      float2 a0{0.f, 0.f}, a1{0.f, 0.f}, a2{0.f, 0.f}, a3{0.f, 0.f};

      for (int i = s; i < e; i += 16) {
        int sv[16], dv[16]; float vv[16];
        #pragma unroll
        for (int t = 0; t < 16; ++t) {
          int idx = i + t;
          bool m = idx < e;
          if (!m) idx = e - 1;               // clamped, in-bounds
          sv[t] = src[idx];
          dv[t] = dst[idx];                  // masked: == cur -> no flush
          float vl = val[idx];
          vv[t] = m ? vl : 0.f;
        }
        int g[16];
        #pragma unroll
        for (int t = 0; t < 16; ++t)
          g[t] = *(const int*)&xb[(long)sv[t] * D_IN + lane * 2];
        #pragma unroll
        for (int t = 0; t < 16; ++t) {
          if (dv[t] != cur) {                // wave-uniform run boundary
            float fx = (a0.x + a1.x) + (a2.x + a3.x);
            float fy = (a0.y + a1.y) + (a2.y + a3.y);
            fx = fmaf(scale, bflo(xg), fx);
            fy = fmaf(scale, bfhi(xg), fy);
            *(int*)&As[cur - m0][lane * 2] = pack_bf2(fx, fy);
            a0 = float2{0.f, 0.f}; a1 = float2{0.f, 0.f};
            a2 = float2{0.f, 0.f}; a3 = float2{0.f, 0.f};
            cur = dv[t];
            xg = *(const int*)&xb[(long)cur * D_IN + lane * 2];  // prefetch
          }
          float2* aa = (t & 3) == 0 ? &a0 : (t & 3) == 1 ? &a1
                     : (t & 3) == 2 ? &a2 : &a3;   // static after unroll
          aa->x = fmaf(vv[t], bflo(g[t]), aa->x);
          aa->y = fmaf(vv[t], bfhi(g[t]), aa->y);
        }
      }
      // final flush
      {
        float fx = (a0.x + a1.x) + (a2.x + a3.x);
        float fy = (a0.y + a1.y) + (a2.y + a3.y);
        fx = fmaf(scale, bflo(xg), fx);
        fy = fmaf(scale, bfhi(xg), fy);
        *(int*)&As[cur - m0][lane * 2] = pack_bf2(fx, fy);
      }
    }
  }

  // W1 fragments: wave covers h cols [wave*64, wave*64+64). 64 VGPRs.
  bf16x8 w1f[4][4];  // [nf][ks]
  #pragma unroll
  for (int nf = 0; nf < 4; ++nf) {
    int n = wave * 64 + nf * 16 + l15;
    #pragma unroll
    for (int ks = 0; ks < 4; ++ks)
      w1f[nf][ks] = *(const bf16x8*)&W1t[(long)n * D_IN + ks * 32 + quad * 8];
  }
  __syncthreads();

  // ---- Phase C1: h[0:64, wave*64 : wave*64+64) = relu(As @ W1 + b1) ----
  f32x4 acc[4][4] = {};  // [mf][nf]
  #pragma unroll
  for (int ks = 0; ks < 4; ++ks) {
    int kq = ks * 32 + quad * 8;
    bf16x8 a[4];
    #pragma unroll
    for (int mf = 0; mf < 4; ++mf)
      a[mf] = *(const bf16x8*)&As[mf * 16 + l15][kq];
    #pragma unroll
    for (int mf = 0; mf < 4; ++mf)
      #pragma unroll
      for (int nf = 0; nf < 4; ++nf)
        acc[mf][nf] = __builtin_amdgcn_mfma_f32_16x16x32_bf16(
            a[mf], w1f[nf][ks], acc[mf][nf], 0, 0, 0);
  }

  #pragma unroll
  for (int nf = 0; nf < 4; ++nf) {
    int col = wave * 64 + nf * 16 + l15;
    float bv = b1[col];
    #pragma unroll
    for (int mf = 0; mf < 4; ++mf)
      #pragma unroll
      for (int r = 0; r < 4; ++r)
        Hs[mf * 16 + quad * 4 + r][col] = (bf16)fmaxf(acc[mf][nf][r] + bv, 0.f);
  }

  // W2 fragments: wave covers out cols [wave*32, wave*32+32). 64 VGPRs.
  bf16x8 w2f[2][8];  // [nf2][ks2]
  #pragma unroll
  for (int nf2 = 0; nf2 < 2; ++nf2) {
    int n = wave * 32 + nf2 * 16 + l15;
    #pragma unroll
    for (int ks2 = 0; ks2 < 8; ++ks2)
      w2f[nf2][ks2] = *(const bf16x8*)&W2t[(long)n * D_HID + ks2 * 32 + quad * 8];
  }
  __syncthreads();

  // ---- Phase C2: out[0:64, wave*32 : wave*32+32) = Hs @ W2 + b2 ----
  f32x4 acc2[4][2] = {};  // [mf][nf2]
  #pragma unroll
  for (int ks2 = 0; ks2 < 8; ++ks2) {
    int kq = ks2 * 32 + quad * 8;
    bf16x8 ha[4];
    #pragma unroll
    for (int mf = 0; mf < 4; ++mf)
      ha[mf] = *(const bf16x8*)&Hs[mf * 16 + l15][kq];
    #pragma unroll
    for (int mf = 0; mf < 4; ++mf)
      #pragma unroll
      for (int nf2 = 0; nf2 < 2; ++nf2)
        acc2[mf][nf2] = __builtin_amdgcn_mfma_f32_16x16x32_bf16(
            ha[mf], w2f[nf2][ks2], acc2[mf][nf2], 0, 0, 0);
  }

  #pragma unroll
  for (int nf2 = 0; nf2 < 2; ++nf2) {
    int col = wave * 32 + nf2 * 16 + l15;
    float bv = b2[col];
    #pragma unroll
    for (int mf = 0; mf < 4; ++mf)
      #pragma unroll
      for (int r = 0; r < 4; ++r) {
        int row = m0 + mf * 16 + quad * 4 + r;
        if (row < N_NODES)
          __builtin_nontemporal_store(acc2[mf][nf2][r] + bv,
                                      &out[(long)row * D_OUT + col]);
      }
  }
}

// ---------------------------------------------------------------------------
extern "C" void kernel_launch(void* const* d_in, const int* in_sizes, int n_in,
                              void* d_out, int out_size, void* d_ws, size_t ws_size,
                              hipStream_t stream) {
  const float* x    = (const float*)d_in[0];
  const int*   esrc = (const int*)d_in[1];
  const int*   edst = (const int*)d_in[2];
  const float* evl  = (const float*)d_in[3];
  const float* eps  = (const float*)d_in[4];
  const float* w1   = (const float*)d_in[5];
  const float* b1   = (const float*)d_in[6];
  const float* w2   = (const float*)d_in[7];
  const float* b2   = (const float*)d_in[8];
  float* out = (float*)d_out;

  // workspace layout (16B aligned): no aggb anymore
  bf16* xb   = (bf16*)d_ws;                          // 12.8 MB
  bf16* w1t  = xb + (size_t)N_NODES * D_IN;          // 64 KB
  bf16* w2t  = w1t + D_IN * D_HID;                   // 64 KB
  int*  offs = (int*)(w2t + D_HID * D_OUT);          // 200 KB

  prep_csr_kernel<<<(N_NODES * D_IN / 4) / 256, 256, 0, stream>>>(
      x, edst, w1, w2, xb, w1t, w2t, offs);
  gin_fused<<<(N_NODES + 63) / 64, 256, 0, stream>>>(
      xb, esrc, edst, evl, offs, eps, w1t, w2t, b1, b2, out);
}

// Round 5
// 193.051 us; speedup vs baseline: 2.8928x; 1.0523x over previous
//
#include <hip/hip_runtime.h>
#include <hip/hip_bf16.h>
#include <cstdint>

#define N_NODES 50000
#define N_EDGES 800000
#define D_IN 128
#define D_HID 256
#define D_OUT 128
#define NPW 4  // nodes per wave in agg kernel

typedef __bf16 bf16;
typedef __bf16 bf16x8 __attribute__((ext_vector_type(8)));
typedef __bf16 bf16x4 __attribute__((ext_vector_type(4)));
typedef float f32x4 __attribute__((ext_vector_type(4)));

__device__ __forceinline__ float bflo(int p) {
  return __uint_as_float((unsigned)p << 16);
}
__device__ __forceinline__ float bfhi(int p) {
  return __uint_as_float((unsigned)p & 0xffff0000u);
}
__device__ __forceinline__ int pack_bf2(float fx, float fy) {
  union { struct { bf16 x, y; } h; int i; } u;
  u.h.x = (bf16)fx; u.h.y = (bf16)fy;
  return u.i;
}

// ---------------------------------------------------------------------------
// Kernel 1: prep + CSR fused (unchanged — ~8 us).
// ---------------------------------------------------------------------------
__global__ __launch_bounds__(256) void prep_csr_kernel(
    const float* __restrict__ x, const int* __restrict__ dst,
    const float* __restrict__ w1, const float* __restrict__ w2,
    bf16* __restrict__ xb, bf16* __restrict__ w1t, bf16* __restrict__ w2t,
    int* __restrict__ offs) {
  const int i = blockIdx.x * 256 + threadIdx.x;
  float4 v = ((const float4*)x)[i];
  ((bf16x4*)xb)[i] = bf16x4{(bf16)v.x, (bf16)v.y, (bf16)v.z, (bf16)v.w};
  if (i < D_IN * D_HID) {            // 32768
    int k = i >> 8, n = i & 255;     // w1[k][n]
    w1t[n * D_IN + k] = (bf16)w1[i];
  } else if (i < 2 * D_IN * D_HID) { // next 32768
    int j = i - D_IN * D_HID;
    int k = j >> 7, n = j & 127;     // w2[k][n]
    w2t[n * D_HID + k] = (bf16)w2[j];
  }
  if (i < N_EDGES) {
    const int b = dst[i];
    const int a = (i == 0) ? -1 : dst[i - 1];
    for (int n = a + 1; n <= b; ++n) offs[n] = i;
    if (i == N_EDGES - 1)
      for (int n = b + 1; n <= N_NODES; ++n) offs[n] = N_EDGES;
  }
}

// ---------------------------------------------------------------------------
// Kernel 2: aggregation, 4 nodes per wave, ZERO LDS (occupancy is the lever:
// r3 showed gather throughput ~ resident waves). 12500 waves / 3125 blocks.
// Run boundaries derived from the 5 wave-uniform offs values via scalar
// compares — no dst[] loads (per-edge metadata drops 3 -> 2 loads).
// 16-deep gather batches, clamp+mask tail, 4 rotating f32 accumulators,
// self-term (1+eps)*x prefetched at run start and folded at flush -> single
// bf16 rounding per output. Degree-0 nodes via offs-equality pre-check.
// ---------------------------------------------------------------------------
__global__ __launch_bounds__(256) void agg_kernel(
    const bf16* __restrict__ xb, const int* __restrict__ src,
    const float* __restrict__ val, const int* __restrict__ offs,
    const float* __restrict__ eps, bf16* __restrict__ aggb) {
  const int wid = (blockIdx.x << 2) | (threadIdx.x >> 6);  // [0,12500)
  const int lane = threadIdx.x & 63;
  const int base = wid * NPW;
  const float scale = 1.0f + eps[0];

  int o0 = __builtin_amdgcn_readfirstlane(offs[base]);
  int o1 = __builtin_amdgcn_readfirstlane(offs[base + 1]);
  int o2 = __builtin_amdgcn_readfirstlane(offs[base + 2]);
  int o3 = __builtin_amdgcn_readfirstlane(offs[base + 3]);
  int o4 = __builtin_amdgcn_readfirstlane(offs[base + 4]);

  // degree-0 nodes (P ~ e^-16: branch essentially never taken)
  if (o0 == o1 || o1 == o2 || o2 == o3 || o3 == o4) {
    #pragma unroll
    for (int j = 0; j < NPW; ++j) {
      int lo = (j == 0) ? o0 : (j == 1) ? o1 : (j == 2) ? o2 : o3;
      int hi = (j == 0) ? o1 : (j == 1) ? o2 : (j == 2) ? o3 : o4;
      if (lo == hi) {
        int xg = *(const int*)&xb[(long)(base + j) * D_IN + lane * 2];
        __builtin_nontemporal_store(
            pack_bf2(scale * bflo(xg), scale * bfhi(xg)),
            (int*)&aggb[(long)(base + j) * D_IN + lane * 2]);
      }
    }
  }

  const int s = o0, e = o4;
  if (e <= s) return;

  int curj = (s >= o1) + (s >= o2) + (s >= o3);
  int xg = *(const int*)&xb[(long)(base + curj) * D_IN + lane * 2];
  float2 a0{0.f, 0.f}, a1{0.f, 0.f}, a2{0.f, 0.f}, a3{0.f, 0.f};

  for (int i = s; i < e; i += 16) {
    int sv[16]; float vv[16];
    #pragma unroll
    for (int t = 0; t < 16; ++t) {
      int idx = i + t;
      bool m = idx < e;
      if (!m) idx = e - 1;               // clamped, in-bounds
      sv[t] = src[idx];
      float vl = val[idx];
      vv[t] = m ? vl : 0.f;              // masked slots contribute 0
    }
    int g[16];
    #pragma unroll
    for (int t = 0; t < 16; ++t)
      g[t] = *(const int*)&xb[(long)sv[t] * D_IN + lane * 2];
    #pragma unroll
    for (int t = 0; t < 16; ++t) {
      int idx = i + t; if (idx >= e) idx = e - 1;          // uniform
      int j = (idx >= o1) + (idx >= o2) + (idx >= o3);     // scalar compares
      if (j != curj) {                   // wave-uniform run boundary
        float fx = (a0.x + a1.x) + (a2.x + a3.x);
        float fy = (a0.y + a1.y) + (a2.y + a3.y);
        fx = fmaf(scale, bflo(xg), fx);
        fy = fmaf(scale, bfhi(xg), fy);
        __builtin_nontemporal_store(
            pack_bf2(fx, fy),
            (int*)&aggb[(long)(base + curj) * D_IN + lane * 2]);
        a0 = float2{0.f, 0.f}; a1 = float2{0.f, 0.f};
        a2 = float2{0.f, 0.f}; a3 = float2{0.f, 0.f};
        curj = j;
        xg = *(const int*)&xb[(long)(base + curj) * D_IN + lane * 2];
      }
      float2* aa = (t & 3) == 0 ? &a0 : (t & 3) == 1 ? &a1
                 : (t & 3) == 2 ? &a2 : &a3;   // static after unroll
      aa->x = fmaf(vv[t], bflo(g[t]), aa->x);
      aa->y = fmaf(vv[t], bfhi(g[t]), aa->y);
    }
  }
  // final flush
  {
    float fx = (a0.x + a1.x) + (a2.x + a3.x);
    float fy = (a0.y + a1.y) + (a2.y + a3.y);
    fx = fmaf(scale, bflo(xg), fx);
    fy = fmaf(scale, bfhi(xg), fy);
    __builtin_nontemporal_store(
        pack_bf2(fx, fy),
        (int*)&aggb[(long)(base + curj) * D_IN + lane * 2]);
  }
}

// ---------------------------------------------------------------------------
// Kernel 3: FUSED 2-layer MLP (round-1 structure, ~13 us). h lives in LDS.
// Fragment layouts (verified): A: a[j]=A[l15][quad*8+j];
//   B: b[j]=Wt[l15][quad*8+j]; C: row=quad*4+r, col=l15.
// LDS = 17.4KB (As) + 33.8KB (Hs) = 51.2KB -> 3 blocks/CU.
// ---------------------------------------------------------------------------
__global__ __launch_bounds__(256) void mlp_fused(
    const bf16* __restrict__ A, const bf16* __restrict__ W1t,
    const bf16* __restrict__ W2t, const float* __restrict__ b1,
    const float* __restrict__ b2, float* __restrict__ out) {
  constexpr int LDA = 136;  // 272B row stride: 2-way bank aliasing only
  constexpr int LDH = 264;  // 528B row stride: 2-way bank aliasing only
  __shared__ alignas(16) bf16 As[64][LDA];
  __shared__ alignas(16) bf16 Hs[64][LDH];

  const int tid = threadIdx.x;
  const int m0 = blockIdx.x * 64;
  const int wave = tid >> 6;
  const int lane = tid & 63;
  const int l15 = lane & 15;
  const int quad = lane >> 4;

  #pragma unroll
  for (int it = 0; it < 4; ++it) {
    int idx = tid + it * 256;          // 0..1023
    int r = idx >> 4;
    int c8 = (idx & 15) << 3;
    int row = m0 + r; if (row >= N_NODES) row = N_NODES - 1;
    *(bf16x8*)&As[r][c8] = *(const bf16x8*)&A[(long)row * D_IN + c8];
  }

  bf16x8 w1f[4][4];  // [nf][ks]
  #pragma unroll
  for (int nf = 0; nf < 4; ++nf) {
    int n = wave * 64 + nf * 16 + l15;
    #pragma unroll
    for (int ks = 0; ks < 4; ++ks)
      w1f[nf][ks] = *(const bf16x8*)&W1t[(long)n * D_IN + ks * 32 + quad * 8];
  }
  __syncthreads();

  // Phase 1: h[0:64, wave*64 : wave*64+64) = relu(As @ W1 + b1)
  f32x4 acc[4][4] = {};  // [mf][nf]
  #pragma unroll
  for (int ks = 0; ks < 4; ++ks) {
    int kq = ks * 32 + quad * 8;
    bf16x8 a[4];
    #pragma unroll
    for (int mf = 0; mf < 4; ++mf)
      a[mf] = *(const bf16x8*)&As[mf * 16 + l15][kq];
    #pragma unroll
    for (int mf = 0; mf < 4; ++mf)
      #pragma unroll
      for (int nf = 0; nf < 4; ++nf)
        acc[mf][nf] = __builtin_amdgcn_mfma_f32_16x16x32_bf16(
            a[mf], w1f[nf][ks], acc[mf][nf], 0, 0, 0);
  }

  #pragma unroll
  for (int nf = 0; nf < 4; ++nf) {
    int col = wave * 64 + nf * 16 + l15;
    float bv = b1[col];
    #pragma unroll
    for (int mf = 0; mf < 4; ++mf)
      #pragma unroll
      for (int r = 0; r < 4; ++r)
        Hs[mf * 16 + quad * 4 + r][col] = (bf16)fmaxf(acc[mf][nf][r] + bv, 0.f);
  }

  bf16x8 w2f[2][8];  // [nf2][ks2]
  #pragma unroll
  for (int nf2 = 0; nf2 < 2; ++nf2) {
    int n = wave * 32 + nf2 * 16 + l15;
    #pragma unroll
    for (int ks2 = 0; ks2 < 8; ++ks2)
      w2f[nf2][ks2] = *(const bf16x8*)&W2t[(long)n * D_HID + ks2 * 32 + quad * 8];
  }
  __syncthreads();

  // Phase 2: out[0:64, wave*32 : wave*32+32) = Hs @ W2 + b2
  f32x4 acc2[4][2] = {};  // [mf][nf2]
  #pragma unroll
  for (int ks2 = 0; ks2 < 8; ++ks2) {
    int kq = ks2 * 32 + quad * 8;
    bf16x8 ha[4];
    #pragma unroll
    for (int mf = 0; mf < 4; ++mf)
      ha[mf] = *(const bf16x8*)&Hs[mf * 16 + l15][kq];
    #pragma unroll
    for (int mf = 0; mf < 4; ++mf)
      #pragma unroll
      for (int nf2 = 0; nf2 < 2; ++nf2)
        acc2[mf][nf2] = __builtin_amdgcn_mfma_f32_16x16x32_bf16(
            ha[mf], w2f[nf2][ks2], acc2[mf][nf2], 0, 0, 0);
  }

  #pragma unroll
  for (int nf2 = 0; nf2 < 2; ++nf2) {
    int col = wave * 32 + nf2 * 16 + l15;
    float bv = b2[col];
    #pragma unroll
    for (int mf = 0; mf < 4; ++mf)
      #pragma unroll
      for (int r = 0; r < 4; ++r) {
        int row = m0 + mf * 16 + quad * 4 + r;
        if (row < N_NODES)
          __builtin_nontemporal_store(acc2[mf][nf2][r] + bv,
                                      &out[(long)row * D_OUT + col]);
      }
  }
}

// ---------------------------------------------------------------------------
extern "C" void kernel_launch(void* const* d_in, const int* in_sizes, int n_in,
                              void* d_out, int out_size, void* d_ws, size_t ws_size,
                              hipStream_t stream) {
  const float* x    = (const float*)d_in[0];
  const int*   esrc = (const int*)d_in[1];
  const int*   edst = (const int*)d_in[2];
  const float* evl  = (const float*)d_in[3];
  const float* eps  = (const float*)d_in[4];
  const float* w1   = (const float*)d_in[5];
  const float* b1   = (const float*)d_in[6];
  const float* w2   = (const float*)d_in[7];
  const float* b2   = (const float*)d_in[8];
  float* out = (float*)d_out;

  // workspace layout (16B aligned)
  bf16* aggb = (bf16*)d_ws;                          // 12.8 MB
  bf16* xb   = aggb + (size_t)N_NODES * D_IN;        // 12.8 MB
  bf16* w1t  = xb + (size_t)N_NODES * D_IN;          // 64 KB
  bf16* w2t  = w1t + D_IN * D_HID;                   // 64 KB
  int*  offs = (int*)(w2t + D_HID * D_OUT);          // 200 KB

  prep_csr_kernel<<<(N_NODES * D_IN / 4) / 256, 256, 0, stream>>>(
      x, edst, w1, w2, xb, w1t, w2t, offs);
  agg_kernel<<<(N_NODES / NPW) / 4, 256, 0, stream>>>(
      xb, esrc, evl, offs, eps, aggb);
  mlp_fused<<<(N_NODES + 63) / 64, 256, 0, stream>>>(
      aggb, w1t, w2t, b1, b2, out);
}

// Round 6
// 148.601 us; speedup vs baseline: 3.7581x; 1.2991x over previous
//
#include <hip/hip_runtime.h>
#include <hip/hip_bf16.h>
#include <cstdint>

#define N_NODES 50000
#define N_EDGES 800000
#define D_IN 128
#define D_HID 256
#define D_OUT 128

typedef __bf16 bf16;
typedef __bf16 bf16x8 __attribute__((ext_vector_type(8)));
typedef __bf16 bf16x4 __attribute__((ext_vector_type(4)));
typedef float f32x4 __attribute__((ext_vector_type(4)));
typedef unsigned int u32x4 __attribute__((ext_vector_type(4)));

__device__ __forceinline__ float bflo(unsigned p) {
  return __uint_as_float(p << 16);
}
__device__ __forceinline__ float bfhi(unsigned p) {
  return __uint_as_float(p & 0xffff0000u);
}
__device__ __forceinline__ unsigned pack_bf2(float fx, float fy) {
  union { struct { bf16 x, y; } h; unsigned i; } u;
  u.h.x = (bf16)fx; u.h.y = (bf16)fy;
  return u.i;
}

// ---------------------------------------------------------------------------
// Kernel 1: prep + CSR fused (unchanged — ~8 us).
//  - xb = bf16(x); w1t/w2t transposed bf16 weights;
//  - offs[] CSR row offsets from SORTED edge_dst (boundary scatter).
// ---------------------------------------------------------------------------
__global__ __launch_bounds__(256) void prep_csr_kernel(
    const float* __restrict__ x, const int* __restrict__ dst,
    const float* __restrict__ w1, const float* __restrict__ w2,
    bf16* __restrict__ xb, bf16* __restrict__ w1t, bf16* __restrict__ w2t,
    int* __restrict__ offs) {
  const int i = blockIdx.x * 256 + threadIdx.x;
  float4 v = ((const float4*)x)[i];
  ((bf16x4*)xb)[i] = bf16x4{(bf16)v.x, (bf16)v.y, (bf16)v.z, (bf16)v.w};
  if (i < D_IN * D_HID) {            // 32768
    int k = i >> 8, n = i & 255;     // w1[k][n]
    w1t[n * D_IN + k] = (bf16)w1[i];
  } else if (i < 2 * D_IN * D_HID) { // next 32768
    int j = i - D_IN * D_HID;
    int k = j >> 7, n = j & 127;     // w2[k][n]
    w2t[n * D_HID + k] = (bf16)w2[j];
  }
  if (i < N_EDGES) {
    const int b = dst[i];
    const int a = (i == 0) ? -1 : dst[i - 1];
    for (int n = a + 1; n <= b; ++n) offs[n] = i;
    if (i == N_EDGES - 1)
      for (int n = b + 1; n <= N_NODES; ++n) offs[n] = N_EDGES;
  }
}

// ---------------------------------------------------------------------------
// Kernel 2: aggregation, ONE node per wave (proven-best residency: 50k waves),
// QUARTER-WAVE EDGE PACKING: 16 lanes x 8 channels (dwordx4 = 16B) cover one
// 256B xb row, so one gather instruction serves 4 edges. Per 16-edge batch:
// 4 sv + 4 vv + 4 gather = 12 VMEM (r1 had 48) -> 4x fewer dependent latency
// chains per edge at the same bytes-in-flight. No dst loads, no run/flush
// logic, no serial remainder (clamp+mask batches). Cross-quarter reduction
// via 2 shfl_xor levels once per node; lanes 0-15 store 16B NT.
// Self-term (1+eps)*x folded after reduction -> single bf16 rounding.
// Zero LDS, ~55 VGPR -> full occupancy eligible. grid: 12500 x 256.
// ---------------------------------------------------------------------------
__global__ __launch_bounds__(256) void agg_kernel(
    const bf16* __restrict__ xb, const int* __restrict__ src,
    const float* __restrict__ val, const int* __restrict__ offs,
    const float* __restrict__ eps, bf16* __restrict__ aggb) {
  const int node = (blockIdx.x << 2) | (threadIdx.x >> 6);  // [0, 50000)
  const int lane = threadIdx.x & 63;
  const int q = lane >> 4;          // which edge of the 4-pack
  const int c8 = (lane & 15) << 3;  // first of this lane's 8 channels
  const float scale = 1.0f + eps[0];

  const int s = __builtin_amdgcn_readfirstlane(offs[node]);
  const int e = __builtin_amdgcn_readfirstlane(offs[node + 1]);

  // self-row (independent; issued early)
  const u32x4 xg = *(const u32x4*)&xb[(long)node * D_IN + c8];

  float a0 = 0.f, a1 = 0.f, a2 = 0.f, a3 = 0.f,
        a4 = 0.f, a5 = 0.f, a6 = 0.f, a7 = 0.f;

  for (int i = s; i < e; i += 16) {   // 16 edges per iteration, 4 per quarter
    int id[4]; int sv[4]; float vv[4];
    #pragma unroll
    for (int t = 0; t < 4; ++t) {
      int raw = i + 4 * t + q;
      id[t] = (raw < e) ? raw : (e - 1);   // clamped, in-bounds
    }
    #pragma unroll
    for (int t = 0; t < 4; ++t) sv[t] = src[id[t]];
    #pragma unroll
    for (int t = 0; t < 4; ++t) {
      float vl = val[id[t]];
      vv[t] = (i + 4 * t + q < e) ? vl : 0.f;  // masked slots contribute 0
    }
    u32x4 g[4];
    #pragma unroll
    for (int t = 0; t < 4; ++t)
      g[t] = *(const u32x4*)&xb[(long)sv[t] * D_IN + c8];
    #pragma unroll
    for (int t = 0; t < 4; ++t) {
      a0 = fmaf(vv[t], bflo(g[t][0]), a0);
      a1 = fmaf(vv[t], bfhi(g[t][0]), a1);
      a2 = fmaf(vv[t], bflo(g[t][1]), a2);
      a3 = fmaf(vv[t], bfhi(g[t][1]), a3);
      a4 = fmaf(vv[t], bflo(g[t][2]), a4);
      a5 = fmaf(vv[t], bfhi(g[t][2]), a5);
      a6 = fmaf(vv[t], bflo(g[t][3]), a6);
      a7 = fmaf(vv[t], bfhi(g[t][3]), a7);
    }
  }

  // reduce the 4 quarter-wave partials (each quarter holds the same 8
  // channels for a disjoint edge subset)
  a0 += __shfl_xor(a0, 16); a0 += __shfl_xor(a0, 32);
  a1 += __shfl_xor(a1, 16); a1 += __shfl_xor(a1, 32);
  a2 += __shfl_xor(a2, 16); a2 += __shfl_xor(a2, 32);
  a3 += __shfl_xor(a3, 16); a3 += __shfl_xor(a3, 32);
  a4 += __shfl_xor(a4, 16); a4 += __shfl_xor(a4, 32);
  a5 += __shfl_xor(a5, 16); a5 += __shfl_xor(a5, 32);
  a6 += __shfl_xor(a6, 16); a6 += __shfl_xor(a6, 32);
  a7 += __shfl_xor(a7, 16); a7 += __shfl_xor(a7, 32);

  if (lane < 16) {
    // fold self-term; single f32->bf16 rounding per output channel
    a0 = fmaf(scale, bflo(xg[0]), a0);
    a1 = fmaf(scale, bfhi(xg[0]), a1);
    a2 = fmaf(scale, bflo(xg[1]), a2);
    a3 = fmaf(scale, bfhi(xg[1]), a3);
    a4 = fmaf(scale, bflo(xg[2]), a4);
    a5 = fmaf(scale, bfhi(xg[2]), a5);
    a6 = fmaf(scale, bflo(xg[3]), a6);
    a7 = fmaf(scale, bfhi(xg[3]), a7);
    u32x4 o;
    o[0] = pack_bf2(a0, a1);
    o[1] = pack_bf2(a2, a3);
    o[2] = pack_bf2(a4, a5);
    o[3] = pack_bf2(a6, a7);
    __builtin_nontemporal_store(o, (u32x4*)&aggb[(long)node * D_IN + c8]);
  }
}

// ---------------------------------------------------------------------------
// Kernel 3: FUSED 2-layer MLP (unchanged — ~13 us). h lives in LDS.
// Fragment layouts (verified): A: a[j]=A[l15][quad*8+j];
//   B: b[j]=Wt[l15][quad*8+j]; C: row=quad*4+r, col=l15.
// LDS = 17.4KB (As) + 33.8KB (Hs) = 51.2KB -> 3 blocks/CU.
// ---------------------------------------------------------------------------
__global__ __launch_bounds__(256) void mlp_fused(
    const bf16* __restrict__ A, const bf16* __restrict__ W1t,
    const bf16* __restrict__ W2t, const float* __restrict__ b1,
    const float* __restrict__ b2, float* __restrict__ out) {
  constexpr int LDA = 136;  // 272B row stride: 2-way bank aliasing only
  constexpr int LDH = 264;  // 528B row stride: 2-way bank aliasing only
  __shared__ alignas(16) bf16 As[64][LDA];
  __shared__ alignas(16) bf16 Hs[64][LDH];

  const int tid = threadIdx.x;
  const int m0 = blockIdx.x * 64;
  const int wave = tid >> 6;
  const int lane = tid & 63;
  const int l15 = lane & 15;
  const int quad = lane >> 4;

  #pragma unroll
  for (int it = 0; it < 4; ++it) {
    int idx = tid + it * 256;          // 0..1023
    int r = idx >> 4;
    int c8 = (idx & 15) << 3;
    int row = m0 + r; if (row >= N_NODES) row = N_NODES - 1;
    *(bf16x8*)&As[r][c8] = *(const bf16x8*)&A[(long)row * D_IN + c8];
  }

  bf16x8 w1f[4][4];  // [nf][ks]
  #pragma unroll
  for (int nf = 0; nf < 4; ++nf) {
    int n = wave * 64 + nf * 16 + l15;
    #pragma unroll
    for (int ks = 0; ks < 4; ++ks)
      w1f[nf][ks] = *(const bf16x8*)&W1t[(long)n * D_IN + ks * 32 + quad * 8];
  }
  __syncthreads();

  // Phase 1: h[0:64, wave*64 : wave*64+64) = relu(As @ W1 + b1)
  f32x4 acc[4][4] = {};  // [mf][nf]
  #pragma unroll
  for (int ks = 0; ks < 4; ++ks) {
    int kq = ks * 32 + quad * 8;
    bf16x8 a[4];
    #pragma unroll
    for (int mf = 0; mf < 4; ++mf)
      a[mf] = *(const bf16x8*)&As[mf * 16 + l15][kq];
    #pragma unroll
    for (int mf = 0; mf < 4; ++mf)
      #pragma unroll
      for (int nf = 0; nf < 4; ++nf)
        acc[mf][nf] = __builtin_amdgcn_mfma_f32_16x16x32_bf16(
            a[mf], w1f[nf][ks], acc[mf][nf], 0, 0, 0);
  }

  #pragma unroll
  for (int nf = 0; nf < 4; ++nf) {
    int col = wave * 64 + nf * 16 + l15;
    float bv = b1[col];
    #pragma unroll
    for (int mf = 0; mf < 4; ++mf)
      #pragma unroll
      for (int r = 0; r < 4; ++r)
        Hs[mf * 16 + quad * 4 + r][col] = (bf16)fmaxf(acc[mf][nf][r] + bv, 0.f);
  }

  bf16x8 w2f[2][8];  // [nf2][ks2]
  #pragma unroll
  for (int nf2 = 0; nf2 < 2; ++nf2) {
    int n = wave * 32 + nf2 * 16 + l15;
    #pragma unroll
    for (int ks2 = 0; ks2 < 8; ++ks2)
      w2f[nf2][ks2] = *(const bf16x8*)&W2t[(long)n * D_HID + ks2 * 32 + quad * 8];
  }
  __syncthreads();

  // Phase 2: out[0:64, wave*32 : wave*32+32) = Hs @ W2 + b2
  f32x4 acc2[4][2] = {};  // [mf][nf2]
  #pragma unroll
  for (int ks2 = 0; ks2 < 8; ++ks2) {
    int kq = ks2 * 32 + quad * 8;
    bf16x8 ha[4];
    #pragma unroll
    for (int mf = 0; mf < 4; ++mf)
      ha[mf] = *(const bf16x8*)&Hs[mf * 16 + l15][kq];
    #pragma unroll
    for (int mf = 0; mf < 4; ++mf)
      #pragma unroll
      for (int nf2 = 0; nf2 < 2; ++nf2)
        acc2[mf][nf2] = __builtin_amdgcn_mfma_f32_16x16x32_bf16(
            ha[mf], w2f[nf2][ks2], acc2[mf][nf2], 0, 0, 0);
  }

  #pragma unroll
  for (int nf2 = 0; nf2 < 2; ++nf2) {
    int col = wave * 32 + nf2 * 16 + l15;
    float bv = b2[col];
    #pragma unroll
    for (int mf = 0; mf < 4; ++mf)
      #pragma unroll
      for (int r = 0; r < 4; ++r) {
        int row = m0 + mf * 16 + quad * 4 + r;
        if (row < N_NODES)
          __builtin_nontemporal_store(acc2[mf][nf2][r] + bv,
                                      &out[(long)row * D_OUT + col]);
      }
  }
}

// ---------------------------------------------------------------------------
extern "C" void kernel_launch(void* const* d_in, const int* in_sizes, int n_in,
                              void* d_out, int out_size, void* d_ws, size_t ws_size,
                              hipStream_t stream) {
  const float* x    = (const float*)d_in[0];
  const int*   esrc = (const int*)d_in[1];
  const int*   edst = (const int*)d_in[2];
  const float* evl  = (const float*)d_in[3];
  const float* eps  = (const float*)d_in[4];
  const float* w1   = (const float*)d_in[5];
  const float* b1   = (const float*)d_in[6];
  const float* w2   = (const float*)d_in[7];
  const float* b2   = (const float*)d_in[8];
  float* out = (float*)d_out;

  // workspace layout (16B aligned)
  bf16* aggb = (bf16*)d_ws;                          // 12.8 MB
  bf16* xb   = aggb + (size_t)N_NODES * D_IN;        // 12.8 MB
  bf16* w1t  = xb + (size_t)N_NODES * D_IN;          // 64 KB
  bf16* w2t  = w1t + D_IN * D_HID;                   // 64 KB
  int*  offs = (int*)(w2t + D_HID * D_OUT);          // 200 KB

  prep_csr_kernel<<<(N_NODES * D_IN / 4) / 256, 256, 0, stream>>>(
      x, edst, w1, w2, xb, w1t, w2t, offs);
  agg_kernel<<<N_NODES / 4, 256, 0, stream>>>(
      xb, esrc, evl, offs, eps, aggb);
  mlp_fused<<<(N_NODES + 63) / 64, 256, 0, stream>>>(
      aggb, w1t, w2t, b1, b2, out);
}